// Round 6
// baseline (416.016 us; speedup 1.0000x reference)
//
#include <hip/hip_runtime.h>

typedef __bf16 bf16x8 __attribute__((ext_vector_type(8)));
typedef float f32x4 __attribute__((ext_vector_type(4)));
typedef unsigned short u16x8 __attribute__((ext_vector_type(8)));
typedef unsigned short u16x4 __attribute__((ext_vector_type(4)));

__device__ __forceinline__ unsigned short f2bf(float f) {
    return __builtin_bit_cast(unsigned short, (__bf16)f);  // v_cvt RNE
}

__device__ __forceinline__ float fexp2(float x) {
#if __has_builtin(__builtin_amdgcn_exp2f)
    return __builtin_amdgcn_exp2f(x);
#else
    float r; asm("v_exp_f32 %0, %1\n\ts_nop 1" : "=v"(r) : "v"(x)); return r;
#endif
}

__device__ __forceinline__ void gload_lds16(const unsigned short* g, unsigned short* l) {
    __builtin_amdgcn_global_load_lds(
        (const __attribute__((address_space(1))) unsigned int*)g,
        (__attribute__((address_space(3))) unsigned int*)l, 16, 0, 0);
}

#define VMCNT(n) asm volatile("s_waitcnt vmcnt(" #n ")" ::: "memory")

// Q pre-scale: 1/sqrt(64) * log2(e), folded into the QKV GEMM epilogue (Q cols only)
#define QSCALE 0.18033688011112042f

// ---------------- LayerNorm: fp32 in -> bf16 out (E=1024, one row per block) ----------------
__global__ __launch_bounds__(256) void ln_kernel(
    const float* __restrict__ x, const float* __restrict__ g,
    const float* __restrict__ b, unsigned short* __restrict__ out)
{
    const int row = blockIdx.x;
    const int tid = threadIdx.x;
    const float4 v = reinterpret_cast<const float4*>(x + (size_t)row * 1024)[tid];
    float s = v.x + v.y + v.z + v.w;
    float q = v.x * v.x + v.y * v.y + v.z * v.z + v.w * v.w;
#pragma unroll
    for (int off = 32; off >= 1; off >>= 1) {
        s += __shfl_xor(s, off);
        q += __shfl_xor(q, off);
    }
    __shared__ float ss[4], sq[4];
    const int wid = tid >> 6, lane = tid & 63;
    if (lane == 0) { ss[wid] = s; sq[wid] = q; }
    __syncthreads();
    s = ss[0] + ss[1] + ss[2] + ss[3];
    q = sq[0] + sq[1] + sq[2] + sq[3];
    const float mu = s * (1.0f / 1024.0f);
    const float var = q * (1.0f / 1024.0f) - mu * mu;
    const float rs = rsqrtf(var + 1e-5f);
    const float4 gv = reinterpret_cast<const float4*>(g)[tid];
    const float4 bv = reinterpret_cast<const float4*>(b)[tid];
    u16x4 o;
    o[0] = f2bf((v.x - mu) * rs * gv.x + bv.x);
    o[1] = f2bf((v.y - mu) * rs * gv.y + bv.y);
    o[2] = f2bf((v.z - mu) * rs * gv.z + bv.z);
    o[3] = f2bf((v.w - mu) * rs * gv.w + bv.w);
    reinterpret_cast<u16x4*>(out + (size_t)row * 1024)[tid] = o;
}

// ---------------- Weight convert + transpose: W[K][N] fp32 -> Wt[N][K] bf16 ----------------
__global__ __launch_bounds__(256) void convT_kernel(
    const float* __restrict__ W, unsigned short* __restrict__ Wt, int K, int N)
{
    __shared__ float t[32][33];
    const int n0 = blockIdx.x * 32, k0 = blockIdx.y * 32;
    const int tx = threadIdx.x & 31;
    const int ty = threadIdx.x >> 5;
#pragma unroll
    for (int i = 0; i < 4; i++)
        t[ty + 8 * i][tx] = W[(size_t)(k0 + ty + 8 * i) * N + (n0 + tx)];
    __syncthreads();
#pragma unroll
    for (int i = 0; i < 4; i++)
        Wt[(size_t)(n0 + ty + 8 * i) * K + (k0 + tx)] = f2bf(t[tx][ty + 8 * i]);
}

// 4 square E x E transposes in one dispatch (z picks the matrix; dsts contiguous)
__global__ __launch_bounds__(256) void convT4_kernel(
    const float* __restrict__ A0, const float* __restrict__ A1,
    const float* __restrict__ A2, const float* __restrict__ A3,
    unsigned short* __restrict__ Wt)
{
    constexpr int E = 1024;
    const int z = blockIdx.z;
    const float* W = (z == 0) ? A0 : (z == 1) ? A1 : (z == 2) ? A2 : A3;
    unsigned short* dst = Wt + (size_t)z * E * E;
    __shared__ float t[32][33];
    const int n0 = blockIdx.x * 32, k0 = blockIdx.y * 32;
    const int tx = threadIdx.x & 31;
    const int ty = threadIdx.x >> 5;
#pragma unroll
    for (int i = 0; i < 4; i++)
        t[ty + 8 * i][tx] = W[(size_t)(k0 + ty + 8 * i) * E + (n0 + tx)];
    __syncthreads();
#pragma unroll
    for (int i = 0; i < 4; i++)
        dst[(size_t)(n0 + ty + 8 * i) * E + (k0 + tx)] = f2bf(t[tx][ty + 8 * i]);
}

// ---------------- bf16 MFMA GEMM, 8-wave deep pipeline: C = A[M][K] * Bt[N][K]^T ----------------
// BM=256, BN=128, BK=64. 512 threads = 8 waves (4M x 2N), per-wave 64x64 output.
// Triple-buffered LDS (144KB), depth-2 prefetch, counted vmcnt(6) (T4), setprio (T5),
// chunk-XOR swizzled LDS (T2/T21: pre-swizzled global source + swizzled b128 reads).
// EPI 1: fp32 = acc + resid     EPI 2: bf16 = gelu_tanh(acc + bias)
// EPI 3: fp32 = acc + bias + resid   EPI 5: bf16 QKV (Q cols pre-scaled)
template <int EPI>
__global__ __launch_bounds__(512) void gemm256_kernel(
    const unsigned short* __restrict__ A, const unsigned short* __restrict__ Bt,
    const float* __restrict__ bias, const float* __restrict__ resid,
    void* __restrict__ out, int M, int N, int K)
{
    __shared__ unsigned short Al[3][256][64];   // 96 KB
    __shared__ unsigned short Bl[3][128][64];   // 48 KB
    const int tid = threadIdx.x;
    const int lane = tid & 63, wid = tid >> 6;   // 8 waves
    const int wr = wid >> 1, wc = wid & 1;       // 4M x 2N wave grid
    const int li = lane & 15, lg = lane >> 4;

    // bijective XCD-chunked swizzle: each XCD gets a contiguous chunk (x fastest -> A-panel reuse)
    const int nx = N >> 7;
    const int cpx = gridDim.x >> 3;
    const int swz = ((int)blockIdx.x & 7) * cpx + ((int)blockIdx.x >> 3);
    const int bx = swz % nx, by = swz / nx;
    const int m0 = by * 256, n0 = bx * 128;

    // staging: wave w stages A rows [w*32, w*32+32) (4 instrs), B rows [w*16, w*16+16) (2 instrs).
    // LDS chunk (row, c) holds global chunk c ^ (row&7) -> pre-swizzled source address.
    const int srow = lane >> 3;                  // 0..7
    const int sgc = ((lane & 7) ^ srow) * 8;
    const unsigned short* Asrc = A + (size_t)(m0 + wid * 32 + srow) * K + sgc;
    const unsigned short* Bsrc = Bt + (size_t)(n0 + wid * 16 + srow) * K + sgc;

    auto stage = [&](int t, int b) {             // 6 gload_lds per wave
        const int k0 = t << 6;
#pragma unroll
        for (int i = 0; i < 4; i++)
            gload_lds16(Asrc + k0 + (size_t)i * 8 * K, &Al[b][wid * 32 + i * 8][0]);
#pragma unroll
        for (int i = 0; i < 2; i++)
            gload_lds16(Bsrc + k0 + (size_t)i * 8 * K, &Bl[b][wid * 16 + i * 8][0]);
    };

    f32x4 acc[4][4] = {};

    auto compute = [&](int b) {                  // 2 phases x (8 ds_read_b128 + 16 MFMA)
#pragma unroll
        for (int ks = 0; ks < 2; ks++) {
            bf16x8 af[4], bfr[4];
#pragma unroll
            for (int m = 0; m < 4; m++)
                af[m] = *reinterpret_cast<const bf16x8*>(
                    &Al[b][wr * 64 + m * 16 + li][((ks * 4 + lg) ^ (li & 7)) * 8]);
#pragma unroll
            for (int n = 0; n < 4; n++)
                bfr[n] = *reinterpret_cast<const bf16x8*>(
                    &Bl[b][wc * 64 + n * 16 + li][((ks * 4 + lg) ^ (li & 7)) * 8]);
            __builtin_amdgcn_s_setprio(1);
#pragma unroll
            for (int m = 0; m < 4; m++)
#pragma unroll
                for (int n = 0; n < 4; n++)
                    acc[m][n] = __builtin_amdgcn_mfma_f32_16x16x32_bf16(af[m], bfr[n], acc[m][n], 0, 0, 0);
            __builtin_amdgcn_s_setprio(0);
            if (ks == 0) {                       // mid-iter phase barrier (no vm drain)
                __builtin_amdgcn_s_barrier();
                __builtin_amdgcn_sched_barrier(0);
            }
        }
    };

    const int NT = K >> 6;                       // >= 16 here

    // prologue: tiles 0,1 in flight; wait tile 0 (keep tile 1's 6 loads flying)
    stage(0, 0);
    stage(1, 1);
    VMCNT(6);
    __builtin_amdgcn_s_barrier();
    __builtin_amdgcn_sched_barrier(0);

    int cur = 0;
    for (int t = 0; t + 2 < NT; ++t) {
        int nb = cur + 2; if (nb >= 3) nb -= 3;
        stage(t + 2, nb);                        // depth-2 prefetch
        compute(cur);
        VMCNT(6);                                // t+1's 6 loads landed; t+2's may fly
        __builtin_amdgcn_s_barrier();
        __builtin_amdgcn_sched_barrier(0);
        cur = (cur == 2) ? 0 : cur + 1;
    }
    compute(cur);                                // tile NT-2
    VMCNT(0);                                    // drain tile NT-1's loads
    __builtin_amdgcn_s_barrier();
    __builtin_amdgcn_sched_barrier(0);
    cur = (cur == 2) ? 0 : cur + 1;
    compute(cur);                                // tile NT-1

#pragma unroll
    for (int m = 0; m < 4; m++) {
#pragma unroll
        for (int r = 0; r < 4; r++) {
            const int row = m0 + wr * 64 + m * 16 + lg * 4 + r;
#pragma unroll
            for (int n = 0; n < 4; n++) {
                const int col = n0 + wc * 64 + n * 16 + li;
                float v = acc[m][n][r];
                if constexpr (EPI == 1) {
                    reinterpret_cast<float*>(out)[(size_t)row * N + col] =
                        v + resid[(size_t)row * N + col];
                } else if constexpr (EPI == 2) {
                    v += bias[col];
                    float a2 = 1.5957691216f * (v + 0.044715f * v * v * v);
                    a2 = fminf(a2, 80.0f);
                    const float t = __expf(a2);
                    v = v * t * __builtin_amdgcn_rcpf(t + 1.0f);
                    reinterpret_cast<unsigned short*>(out)[(size_t)row * N + col] = f2bf(v);
                } else if constexpr (EPI == 3) {
                    reinterpret_cast<float*>(out)[(size_t)row * N + col] =
                        v + bias[col] + resid[(size_t)row * N + col];
                } else {  // EPI 5: fused QKV, Q columns pre-scaled for exp2 softmax
                    const float sc = (col < 1024) ? QSCALE : 1.0f;
                    reinterpret_cast<unsigned short*>(out)[(size_t)row * N + col] = f2bf(v * sc);
                }
            }
        }
    }
}

// ---------------- Flash attention (causal), no-max exp2 softmax, 1 barrier/tile ----------------
// QKV [8192][3072] (Q pre-scaled by QSCALE). grid 1024 = 4 blocks/CU exactly resident.
__global__ __launch_bounds__(256, 4) void flash_kernel(
    const unsigned short* __restrict__ QKV, unsigned short* __restrict__ O)
{
    constexpr int C = 2048, HD3 = 3072, HD = 1024, NT = 32;
    __shared__ unsigned short Kl[2][64][64];  // [key][d], chunk XOR (row&7)
    __shared__ unsigned short Vt[2][64][64];  // [d][key], chunk XOR (row&7)^(row>>3)
    __shared__ unsigned short Pl[64][64];     // [q][key], chunk rotation +2*(row>>2)
    const int tid = threadIdx.x;
    const int lane = tid & 63, wid = tid >> 6;
    const int li = lane & 15, lg = lane >> 4;
    const int flat = blockIdx.x;
    const int bh = flat & 63;                // one head's 16 blocks share an XCD
    const int pair = flat >> 6;              // 0..15
    const int b = bh >> 4, h = bh & 15;
    const size_t baseQ = ((size_t)b * C) * HD3 + (size_t)h * 64;
    const size_t baseK = baseQ + 1024;
    const size_t baseV = baseQ + 2048;
    const size_t baseO = ((size_t)b * C) * HD + (size_t)h * 64;

    const int srow = lane >> 3;                       // 0..7
    const int sgc = ((lane & 7) ^ srow) * 8;          // K pre-swizzled global chunk
    const int vx = lane & 7;                          // V: d-block [vx*8, vx*8+8)

    const u16x8 onesu = {0x3F80, 0x3F80, 0x3F80, 0x3F80, 0x3F80, 0x3F80, 0x3F80, 0x3F80};
    const bf16x8 ones = __builtin_bit_cast(bf16x8, onesu);

    for (int half = 0; half < 2; half++) {
        const int qt = (half == 0) ? pair : (NT - 1 - pair);
        const int q0 = qt * 64;
        const int qrow = q0 + wid * 16 + li;
        const bf16x8 qa0 = *reinterpret_cast<const bf16x8*>(&QKV[baseQ + (size_t)qrow * HD3 + lg * 8]);
        const bf16x8 qa1 = *reinterpret_cast<const bf16x8*>(&QKV[baseQ + (size_t)qrow * HD3 + 32 + lg * 8]);
        const int myrow0 = q0 + wid * 16 + lg * 4;

        f32x4 acc[4] = {};
        f32x4 accl = {};
        int cur = 0;

        auto stage = [&](int k0s, int buf) {
#pragma unroll
            for (int i = 0; i < 2; i++)
                gload_lds16(&QKV[baseK + (size_t)(k0s + wid * 16 + i * 8 + srow) * HD3 + sgc],
                            &Kl[buf][wid * 16 + i * 8][0]);
#pragma unroll
            for (int i = 0; i < 2; i++) {
                const int lkey = 8 * wid + srow + 32 * i;
                const u16x8 vv = *reinterpret_cast<const u16x8*>(
                    &QKV[baseV + (size_t)(k0s + lkey) * HD3 + vx * 8]);
                const int vc = wid + 4 * i;  // lkey>>3
#pragma unroll
                for (int j = 0; j < 8; j++)
                    Vt[buf][vx * 8 + j][((vc ^ j ^ vx) & 7) * 8 + srow] = vv[j];
            }
        };

        __syncthreads();
        stage(0, 0);
        __syncthreads();

        auto tile_body = [&](int t, bool diag, bool pre) {
            const int k0 = t * 64;
            u16x8 vr0, vr1;
            if (pre) {  // issue next-tile loads early (hide under compute)
                const int kn = k0 + 64;
#pragma unroll
                for (int i = 0; i < 2; i++)
                    gload_lds16(&QKV[baseK + (size_t)(kn + wid * 16 + i * 8 + srow) * HD3 + sgc],
                                &Kl[cur ^ 1][wid * 16 + i * 8][0]);
                vr0 = *reinterpret_cast<const u16x8*>(
                    &QKV[baseV + (size_t)(kn + 8 * wid + srow) * HD3 + vx * 8]);
                vr1 = *reinterpret_cast<const u16x8*>(
                    &QKV[baseV + (size_t)(kn + 8 * wid + srow + 32) * HD3 + vx * 8]);
            }

            // S = Q K^T (Q pre-scaled; S in log2 domain)
            f32x4 s[4] = {};
            __builtin_amdgcn_s_setprio(1);
#pragma unroll
            for (int n = 0; n < 4; n++) {
                const int row = n * 16 + li;
                const bf16x8 kb0 = *reinterpret_cast<const bf16x8*>(
                    &Kl[cur][row][(lg ^ (li & 7)) * 8]);
                const bf16x8 kb1 = *reinterpret_cast<const bf16x8*>(
                    &Kl[cur][row][((4 + lg) ^ (li & 7)) * 8]);
                s[n] = __builtin_amdgcn_mfma_f32_16x16x32_bf16(qa0, kb0, s[n], 0, 0, 0);
                s[n] = __builtin_amdgcn_mfma_f32_16x16x32_bf16(qa1, kb1, s[n], 0, 0, 0);
            }
            __builtin_amdgcn_s_setprio(0);

            // P = exp2(S), causal zeroing on diag tile only
#pragma unroll
            for (int n = 0; n < 4; n++) {
#pragma unroll
                for (int r = 0; r < 4; r++) {
                    float pv = fexp2(s[n][r]);
                    if (diag) {
                        const int key = k0 + n * 16 + li;
                        if (key > myrow0 + r) pv = 0.0f;
                    }
                    Pl[wid * 16 + lg * 4 + r][((2 * n + (li >> 3) + 2 * lg) & 7) * 8 + (li & 7)] = f2bf(pv);
                }
            }

            if (pre) {  // V regs have arrived; fill Vt[next]
#pragma unroll
                for (int j = 0; j < 8; j++)
                    Vt[cur ^ 1][vx * 8 + j][((wid ^ j ^ vx) & 7) * 8 + srow] = vr0[j];
#pragma unroll
                for (int j = 0; j < 8; j++)
                    Vt[cur ^ 1][vx * 8 + j][(((wid + 4) ^ j ^ vx) & 7) * 8 + srow] = vr1[j];
            }

            // O += P V ; row-sums via ones-MFMA
            __builtin_amdgcn_s_setprio(1);
#pragma unroll
            for (int ks = 0; ks < 2; ks++) {
                const bf16x8 pa = *reinterpret_cast<const bf16x8*>(
                    &Pl[wid * 16 + li][((ks * 4 + lg + 2 * (li >> 2)) & 7) * 8]);
#pragma unroll
                for (int n = 0; n < 4; n++) {
                    const int row = n * 16 + li;
                    const bf16x8 vb = *reinterpret_cast<const bf16x8*>(
                        &Vt[cur][row][(((ks * 4 + lg) ^ (row & 7) ^ (row >> 3)) & 7) * 8]);
                    acc[n] = __builtin_amdgcn_mfma_f32_16x16x32_bf16(pa, vb, acc[n], 0, 0, 0);
                }
                accl = __builtin_amdgcn_mfma_f32_16x16x32_bf16(pa, ones, accl, 0, 0, 0);
            }
            __builtin_amdgcn_s_setprio(0);

            __syncthreads();
            cur ^= 1;
        };

        for (int t = 0; t < qt; t++) tile_body(t, false, true);
        tile_body(qt, true, false);

#pragma unroll
        for (int r = 0; r < 4; r++) {
            const float inv = 1.0f / accl[r];
            const int row = myrow0 + r;
#pragma unroll
            for (int n = 0; n < 4; n++)
                O[baseO + (size_t)row * HD + n * 16 + li] = f2bf(acc[n][r] * inv);
        }
    }
}

// ---------------- launch ----------------
extern "C" void kernel_launch(void* const* d_in, const int* in_sizes, int n_in,
                              void* d_out, int out_size, void* d_ws, size_t ws_size,
                              hipStream_t stream) {
    constexpr int B = 4, C = 2048, E = 1024, H = 16, FF = 4096;
    constexpr int M = B * C;  // 8192

    const float* x     = (const float*)d_in[0];
    const float* ln1_g = (const float*)d_in[1];
    const float* ln1_b = (const float*)d_in[2];
    const float* Wq    = (const float*)d_in[3];
    const float* Wk    = (const float*)d_in[4];
    const float* Wv    = (const float*)d_in[5];
    const float* Wo    = (const float*)d_in[6];
    const float* ln2_g = (const float*)d_in[7];
    const float* ln2_b = (const float*)d_in[8];
    const float* W1    = (const float*)d_in[9];
    const float* b1    = (const float*)d_in[10];
    const float* W2    = (const float*)d_in[11];
    const float* b2    = (const float*)d_in[12];

    char* p = (char*)d_ws;
    auto alloc = [&](size_t bytes) { void* r = (void*)p; p += (bytes + 255) & ~(size_t)255; return r; };
    unsigned short* WqT  = (unsigned short*)alloc((size_t)E * E * 2);   // Wq/Wk/Wv/Wo contiguous
    unsigned short* WkT  = (unsigned short*)alloc((size_t)E * E * 2);
    unsigned short* WvT  = (unsigned short*)alloc((size_t)E * E * 2);
    unsigned short* WoT  = (unsigned short*)alloc((size_t)E * E * 2);
    unsigned short* W1T  = (unsigned short*)alloc((size_t)E * FF * 2);
    unsigned short* W2T  = (unsigned short*)alloc((size_t)FF * E * 2);
    unsigned short* hb   = (unsigned short*)alloc((size_t)M * E * 2);
    unsigned short* QKVb = (unsigned short*)alloc((size_t)M * 3 * E * 2);
    unsigned short* attn = (unsigned short*)alloc((size_t)M * E * 2);
    float*          x1   = (float*)alloc((size_t)M * E * 4);
    unsigned short* h2   = (unsigned short*)alloc((size_t)M * E * 2);
    unsigned short* ff   = (unsigned short*)alloc((size_t)M * FF * 2);
    (void)WkT; (void)WvT;

    // weight conversion / transpose (4 square ones fused)
    convT4_kernel<<<dim3(E / 32, E / 32, 4), 256, 0, stream>>>(Wq, Wk, Wv, Wo, WqT);
    convT_kernel<<<dim3(FF / 32, E / 32), 256, 0, stream>>>(W1, W1T, E, FF);
    convT_kernel<<<dim3(E / 32, FF / 32), 256, 0, stream>>>(W2, W2T, FF, E);

    // LN1
    ln_kernel<<<M, 256, 0, stream>>>(x, ln1_g, ln1_b, hb);

    // fused QKV projection (N=3072), Q columns pre-scaled
    gemm256_kernel<5><<<dim3((3 * E / 128) * (M / 256)), 512, 0, stream>>>(
        hb, WqT, nullptr, nullptr, QKVb, M, 3 * E, E);

    // attention
    flash_kernel<<<dim3(1024), 256, 0, stream>>>(QKVb, attn);

    // output projection + residual
    gemm256_kernel<1><<<dim3((E / 128) * (M / 256)), 512, 0, stream>>>(
        attn, WoT, nullptr, x, x1, M, E, E);

    // LN2
    ln_kernel<<<M, 256, 0, stream>>>(x1, ln2_g, ln2_b, h2);

    // FFN
    gemm256_kernel<2><<<dim3((FF / 128) * (M / 256)), 512, 0, stream>>>(
        h2, W1T, b1, nullptr, ff, M, FF, E);
    gemm256_kernel<3><<<dim3((E / 128) * (M / 256)), 512, 0, stream>>>(
        ff, W2T, b2, x1, d_out, M, E, FF);
}

// Round 7
// 410.270 us; speedup vs baseline: 1.0140x; 1.0140x over previous
//
#include <hip/hip_runtime.h>

typedef __bf16 bf16x8 __attribute__((ext_vector_type(8)));
typedef float f32x4 __attribute__((ext_vector_type(4)));
typedef unsigned short u16x8 __attribute__((ext_vector_type(8)));
typedef unsigned short u16x4 __attribute__((ext_vector_type(4)));

__device__ __forceinline__ unsigned short f2bf(float f) {
    return __builtin_bit_cast(unsigned short, (__bf16)f);  // v_cvt RNE
}

__device__ __forceinline__ float fexp2(float x) {
#if __has_builtin(__builtin_amdgcn_exp2f)
    return __builtin_amdgcn_exp2f(x);
#else
    float r; asm("v_exp_f32 %0, %1\n\ts_nop 1" : "=v"(r) : "v"(x)); return r;
#endif
}

__device__ __forceinline__ void gload_lds16(const unsigned short* g, unsigned short* l) {
    __builtin_amdgcn_global_load_lds(
        (const __attribute__((address_space(1))) unsigned int*)g,
        (__attribute__((address_space(3))) unsigned int*)l, 16, 0, 0);
}

#define VMW(n) asm volatile("s_waitcnt vmcnt(" #n ")" ::: "memory")
#define SBAR() __builtin_amdgcn_s_barrier()
#define SCHED0() __builtin_amdgcn_sched_barrier(0)

// Q pre-scale: 1/sqrt(64) * log2(e), folded into the QKV GEMM epilogue (Q cols only)
#define QSCALE 0.18033688011112042f

// ---------------- LayerNorm: fp32 in -> bf16 out (E=1024, one row per block) ----------------
__global__ __launch_bounds__(256) void ln_kernel(
    const float* __restrict__ x, const float* __restrict__ g,
    const float* __restrict__ b, unsigned short* __restrict__ out)
{
    const int row = blockIdx.x;
    const int tid = threadIdx.x;
    const float4 v = reinterpret_cast<const float4*>(x + (size_t)row * 1024)[tid];
    float s = v.x + v.y + v.z + v.w;
    float q = v.x * v.x + v.y * v.y + v.z * v.z + v.w * v.w;
#pragma unroll
    for (int off = 32; off >= 1; off >>= 1) {
        s += __shfl_xor(s, off);
        q += __shfl_xor(q, off);
    }
    __shared__ float ss[4], sq[4];
    const int wid = tid >> 6, lane = tid & 63;
    if (lane == 0) { ss[wid] = s; sq[wid] = q; }
    __syncthreads();
    s = ss[0] + ss[1] + ss[2] + ss[3];
    q = sq[0] + sq[1] + sq[2] + sq[3];
    const float mu = s * (1.0f / 1024.0f);
    const float var = q * (1.0f / 1024.0f) - mu * mu;
    const float rs = rsqrtf(var + 1e-5f);
    const float4 gv = reinterpret_cast<const float4*>(g)[tid];
    const float4 bv = reinterpret_cast<const float4*>(b)[tid];
    u16x4 o;
    o[0] = f2bf((v.x - mu) * rs * gv.x + bv.x);
    o[1] = f2bf((v.y - mu) * rs * gv.y + bv.y);
    o[2] = f2bf((v.z - mu) * rs * gv.z + bv.z);
    o[3] = f2bf((v.w - mu) * rs * gv.w + bv.w);
    reinterpret_cast<u16x4*>(out + (size_t)row * 1024)[tid] = o;
}

// ---------------- Weight convert + transpose: W[K][N] fp32 -> Wt[N][K] bf16 ----------------
__global__ __launch_bounds__(256) void convT_kernel(
    const float* __restrict__ W, unsigned short* __restrict__ Wt, int K, int N)
{
    __shared__ float t[32][33];
    const int n0 = blockIdx.x * 32, k0 = blockIdx.y * 32;
    const int tx = threadIdx.x & 31;
    const int ty = threadIdx.x >> 5;
#pragma unroll
    for (int i = 0; i < 4; i++)
        t[ty + 8 * i][tx] = W[(size_t)(k0 + ty + 8 * i) * N + (n0 + tx)];
    __syncthreads();
#pragma unroll
    for (int i = 0; i < 4; i++)
        Wt[(size_t)(n0 + ty + 8 * i) * K + (k0 + tx)] = f2bf(t[tx][ty + 8 * i]);
}

// 4 square E x E transposes in one dispatch (z picks the matrix; dsts contiguous)
__global__ __launch_bounds__(256) void convT4_kernel(
    const float* __restrict__ A0, const float* __restrict__ A1,
    const float* __restrict__ A2, const float* __restrict__ A3,
    unsigned short* __restrict__ Wt)
{
    constexpr int E = 1024;
    const int z = blockIdx.z;
    const float* W = (z == 0) ? A0 : (z == 1) ? A1 : (z == 2) ? A2 : A3;
    unsigned short* dst = Wt + (size_t)z * E * E;
    __shared__ float t[32][33];
    const int n0 = blockIdx.x * 32, k0 = blockIdx.y * 32;
    const int tx = threadIdx.x & 31;
    const int ty = threadIdx.x >> 5;
#pragma unroll
    for (int i = 0; i < 4; i++)
        t[ty + 8 * i][tx] = W[(size_t)(k0 + ty + 8 * i) * E + (n0 + tx)];
    __syncthreads();
#pragma unroll
    for (int i = 0; i < 4; i++)
        dst[(size_t)(n0 + ty + 8 * i) * E + (k0 + tx)] = f2bf(t[tx][ty + 8 * i]);
}

// ---------------- bf16 MFMA GEMM, 256x256 8-phase schedule: C = A[M][K] * Bt[N][K]^T ----------
// 512 thr = 8 waves (2M x 4N), per-wave 128x64 output (acc[8][4]). BK=64, 2 K-tiles per iter.
// LDS 128KB: A/B each [2 dbuf][256][64]. Per phase: {ds_read subtile, stage half-tile,
// barrier, setprio+16 MFMA, counted vmcnt (never 0 mid-loop), barrier}.  T2+T3+T4+T5+T1.
// Stage map (iter I, tiles u0=2I,u0+1): ph1: A(u1) both halves; ph3/ph4: B0/B1(u0+2);
// ph5: A(u0+2) both; ph7/ph8: B0/B1(u1+2). Min stage->read gap = 4 phases.
// EPI 1: fp32 = acc + resid     EPI 2: bf16 = gelu_tanh(acc + bias)
// EPI 3: fp32 = acc + bias + resid   EPI 5: bf16 QKV (Q cols pre-scaled)
template <int EPI>
__global__ __launch_bounds__(512, 2) void gemm_kernel(
    const unsigned short* __restrict__ A, const unsigned short* __restrict__ Bt,
    const float* __restrict__ bias, const float* __restrict__ resid,
    void* __restrict__ out, int M, int N, int K)
{
    __shared__ __align__(16) unsigned short Al[2][256][64];   // 64 KB
    __shared__ __align__(16) unsigned short Bl[2][256][64];   // 64 KB
    const int tid = threadIdx.x;
    const int lane = tid & 63, wid = tid >> 6;   // 8 waves
    const int wr = wid >> 2, wc = wid & 3;       // 2M x 4N wave grid
    const int li = lane & 15, lg = lane >> 4;

    // bijective XCD-chunked swizzle (all grids are multiples of 8)
    const int nx = N >> 8;
    const int cpx = gridDim.x >> 3;
    const int swz = ((int)blockIdx.x & 7) * cpx + ((int)blockIdx.x >> 3);
    const int bx = swz % nx, by = swz / nx;
    const int m0 = by * 256, n0 = bx * 256;

    // staging: wave w covers rows [w*16, w*16+16) of each 128-row half (2 gload_lds each).
    // LDS chunk (row, c) holds global chunk c ^ (row&7) -> pre-swizzled source (T21).
    const int srow = lane >> 3;                  // 0..7
    const int sgc = ((lane & 7) ^ srow) * 8;
    const unsigned short* aSrc = A + (size_t)(m0 + wid * 16 + srow) * K + sgc;
    const unsigned short* bSrc = Bt + (size_t)(n0 + wid * 16 + srow) * K + sgc;
    unsigned short* aDst = &Al[0][wid * 16][0];
    unsigned short* bDst = &Bl[0][wid * 16][0];

    auto stA = [&](int u, int h) {               // stage A rows [h*128, h*128+128) of K-tile u
        const unsigned short* s = aSrc + (size_t)(h * 128) * K + u * 64;
        unsigned short* d = aDst + (u & 1) * (256 * 64) + h * 128 * 64;
        gload_lds16(s, d);
        gload_lds16(s + (size_t)8 * K, d + 8 * 64);
    };
    auto stB = [&](int u, int h) {
        const unsigned short* s = bSrc + (size_t)(h * 128) * K + u * 64;
        unsigned short* d = bDst + (u & 1) * (256 * 64) + h * 128 * 64;
        gload_lds16(s, d);
        gload_lds16(s + (size_t)8 * K, d + 8 * 64);
    };

    f32x4 acc[8][4] = {};
    bf16x8 af[8], bn0[4], bn1[4];

    auto ldA = [&](int buf, int mh) {            // 8 x ds_read_b128
#pragma unroll
        for (int m = 0; m < 4; m++)
#pragma unroll
            for (int ks = 0; ks < 2; ks++)
                af[m * 2 + ks] = *reinterpret_cast<const bf16x8*>(
                    &Al[buf][wr * 128 + mh * 64 + m * 16 + li][((ks * 4 + lg) ^ (li & 7)) * 8]);
    };
    auto ldB = [&](bf16x8* dst, int buf, int nh) {  // 4 x ds_read_b128
#pragma unroll
        for (int n = 0; n < 2; n++)
#pragma unroll
            for (int ks = 0; ks < 2; ks++)
                dst[n * 2 + ks] = *reinterpret_cast<const bf16x8*>(
                    &Bl[buf][wc * 64 + nh * 32 + n * 16 + li][((ks * 4 + lg) ^ (li & 7)) * 8]);
    };
    auto quad = [&](const bf16x8* bfr, int mh, int nh) {   // 16 MFMA, one C-quadrant x K=64
        __builtin_amdgcn_s_setprio(1);
#pragma unroll
        for (int ks = 0; ks < 2; ks++)
#pragma unroll
            for (int m = 0; m < 4; m++)
#pragma unroll
                for (int n = 0; n < 2; n++)
                    acc[mh * 4 + m][nh * 2 + n] = __builtin_amdgcn_mfma_f32_16x16x32_bf16(
                        af[m * 2 + ks], bfr[n * 2 + ks], acc[mh * 4 + m][nh * 2 + n], 0, 0, 0);
        __builtin_amdgcn_s_setprio(0);
    };

    const int NI = K >> 7;                       // iterations of 2 K-tiles

    // prologue: A(0), B(0), B(1)  (A(1) staged at iter0/ph1)
    stA(0, 0); stA(0, 1); stB(0, 0); stB(0, 1); stB(1, 0); stB(1, 1);
    VMW(4);                                      // A(0)+B(0) landed; B(1) may fly
    SBAR(); SCHED0();

    for (int I = 0; I < NI; ++I) {
        const int u0 = 2 * I;
        const bool hn = (I + 1 < NI);
        // ---- K-tile u0 (buf 0) ----
        // ph1: quad(0,0)
        ldA(0, 0); ldB(bn0, 0, 0);
        stA(u0 + 1, 0); stA(u0 + 1, 1);
        SBAR(); SCHED0();
        quad(bn0, 0, 0);
        VMW(8); SBAR(); SCHED0();
        // ph2: quad(0,1)
        ldB(bn1, 0, 1);
        SBAR(); SCHED0();
        quad(bn1, 0, 1);
        VMW(6); SBAR(); SCHED0();
        // ph3: quad(1,1)
        ldA(0, 1);
        if (hn) stB(u0 + 2, 0);
        SBAR(); SCHED0();
        quad(bn1, 1, 1);
        VMW(6); SBAR(); SCHED0();
        // ph4: quad(1,0)  (bn0 held since ph1)
        if (hn) stB(u0 + 2, 1);
        SBAR(); SCHED0();
        quad(bn0, 1, 0);
        if (hn) { VMW(4); } else { VMW(0); }     // last iter: drain so ph5 reads A(u1)
        SBAR(); SCHED0();
        // ---- K-tile u0+1 (buf 1) ----
        // ph5
        ldA(1, 0); ldB(bn0, 1, 0);
        if (hn) { stA(u0 + 2, 0); stA(u0 + 2, 1); }
        SBAR(); SCHED0();
        quad(bn0, 0, 0);
        VMW(8); SBAR(); SCHED0();
        // ph6
        ldB(bn1, 1, 1);
        SBAR(); SCHED0();
        quad(bn1, 0, 1);
        VMW(6); SBAR(); SCHED0();
        // ph7
        ldA(1, 1);
        if (hn) stB(u0 + 3, 0);
        SBAR(); SCHED0();
        quad(bn1, 1, 1);
        VMW(6); SBAR(); SCHED0();
        // ph8
        if (hn) stB(u0 + 3, 1);
        SBAR(); SCHED0();
        quad(bn0, 1, 0);
        VMW(4); SBAR(); SCHED0();
    }

    // epilogue
#pragma unroll
    for (int ma = 0; ma < 8; ma++) {
#pragma unroll
        for (int r = 0; r < 4; r++) {
            const int row = m0 + wr * 128 + ma * 16 + lg * 4 + r;
#pragma unroll
            for (int n = 0; n < 4; n++) {
                const int col = n0 + wc * 64 + n * 16 + li;
                float v = acc[ma][n][r];
                if constexpr (EPI == 1) {
                    reinterpret_cast<float*>(out)[(size_t)row * N + col] =
                        v + resid[(size_t)row * N + col];
                } else if constexpr (EPI == 2) {
                    v += bias[col];
                    float a2 = 1.5957691216f * (v + 0.044715f * v * v * v);
                    a2 = fminf(a2, 80.0f);
                    const float t = __expf(a2);
                    v = v * t * __builtin_amdgcn_rcpf(t + 1.0f);
                    reinterpret_cast<unsigned short*>(out)[(size_t)row * N + col] = f2bf(v);
                } else if constexpr (EPI == 3) {
                    reinterpret_cast<float*>(out)[(size_t)row * N + col] =
                        v + bias[col] + resid[(size_t)row * N + col];
                } else {  // EPI 5: fused QKV, Q columns pre-scaled for exp2 softmax
                    const float sc = (col < 1024) ? QSCALE : 1.0f;
                    reinterpret_cast<unsigned short*>(out)[(size_t)row * N + col] = f2bf(v * sc);
                }
            }
        }
    }
}

// ---------------- Flash attention (causal), no-max exp2 softmax, 1 barrier/tile ----------------
// QKV [8192][3072] (Q pre-scaled by QSCALE). grid 1024 = 4 blocks/CU exactly resident.
__global__ __launch_bounds__(256, 4) void flash_kernel(
    const unsigned short* __restrict__ QKV, unsigned short* __restrict__ O)
{
    constexpr int C = 2048, HD3 = 3072, HD = 1024, NT = 32;
    __shared__ unsigned short Kl[2][64][64];  // [key][d], chunk XOR (row&7)
    __shared__ unsigned short Vt[2][64][64];  // [d][key], chunk XOR (row&7)^(row>>3)
    __shared__ unsigned short Pl[64][64];     // [q][key], chunk rotation
    const int tid = threadIdx.x;
    const int lane = tid & 63, wid = tid >> 6;
    const int li = lane & 15, lg = lane >> 4;
    const int flat = blockIdx.x;
    const int bh = flat & 63;                // one head's 16 blocks share an XCD
    const int pair = flat >> 6;              // 0..15
    const int b = bh >> 4, h = bh & 15;
    const size_t baseQ = ((size_t)b * C) * HD3 + (size_t)h * 64;
    const size_t baseK = baseQ + 1024;
    const size_t baseV = baseQ + 2048;
    const size_t baseO = ((size_t)b * C) * HD + (size_t)h * 64;

    const int srow = lane >> 3;                       // 0..7
    const int sgc = ((lane & 7) ^ srow) * 8;          // K pre-swizzled global chunk
    const int vx = lane & 7;                          // V: d-block [vx*8, vx*8+8)

    const u16x8 onesu = {0x3F80, 0x3F80, 0x3F80, 0x3F80, 0x3F80, 0x3F80, 0x3F80, 0x3F80};
    const bf16x8 ones = __builtin_bit_cast(bf16x8, onesu);

    for (int half = 0; half < 2; half++) {
        const int qt = (half == 0) ? pair : (NT - 1 - pair);
        const int q0 = qt * 64;
        const int qrow = q0 + wid * 16 + li;
        const bf16x8 qa0 = *reinterpret_cast<const bf16x8*>(&QKV[baseQ + (size_t)qrow * HD3 + lg * 8]);
        const bf16x8 qa1 = *reinterpret_cast<const bf16x8*>(&QKV[baseQ + (size_t)qrow * HD3 + 32 + lg * 8]);
        const int myrow0 = q0 + wid * 16 + lg * 4;

        f32x4 acc[4] = {};
        f32x4 accl = {};
        int cur = 0;

        auto stage = [&](int k0s, int buf) {
#pragma unroll
            for (int i = 0; i < 2; i++)
                gload_lds16(&QKV[baseK + (size_t)(k0s + wid * 16 + i * 8 + srow) * HD3 + sgc],
                            &Kl[buf][wid * 16 + i * 8][0]);
#pragma unroll
            for (int i = 0; i < 2; i++) {
                const int lkey = 8 * wid + srow + 32 * i;
                const u16x8 vv = *reinterpret_cast<const u16x8*>(
                    &QKV[baseV + (size_t)(k0s + lkey) * HD3 + vx * 8]);
                const int vc = wid + 4 * i;  // lkey>>3
#pragma unroll
                for (int j = 0; j < 8; j++)
                    Vt[buf][vx * 8 + j][((vc ^ j ^ vx) & 7) * 8 + srow] = vv[j];
            }
        };

        __syncthreads();
        stage(0, 0);
        __syncthreads();

        auto tile_body = [&](int t, bool diag, bool pre) {
            const int k0 = t * 64;
            u16x8 vr0, vr1;
            if (pre) {  // issue next-tile loads early (hide under compute)
                const int kn = k0 + 64;
#pragma unroll
                for (int i = 0; i < 2; i++)
                    gload_lds16(&QKV[baseK + (size_t)(kn + wid * 16 + i * 8 + srow) * HD3 + sgc],
                                &Kl[cur ^ 1][wid * 16 + i * 8][0]);
                vr0 = *reinterpret_cast<const u16x8*>(
                    &QKV[baseV + (size_t)(kn + 8 * wid + srow) * HD3 + vx * 8]);
                vr1 = *reinterpret_cast<const u16x8*>(
                    &QKV[baseV + (size_t)(kn + 8 * wid + srow + 32) * HD3 + vx * 8]);
            }

            // S = Q K^T (Q pre-scaled; S in log2 domain)
            f32x4 s[4] = {};
            __builtin_amdgcn_s_setprio(1);
#pragma unroll
            for (int n = 0; n < 4; n++) {
                const int row = n * 16 + li;
                const bf16x8 kb0 = *reinterpret_cast<const bf16x8*>(
                    &Kl[cur][row][(lg ^ (li & 7)) * 8]);
                const bf16x8 kb1 = *reinterpret_cast<const bf16x8*>(
                    &Kl[cur][row][((4 + lg) ^ (li & 7)) * 8]);
                s[n] = __builtin_amdgcn_mfma_f32_16x16x32_bf16(qa0, kb0, s[n], 0, 0, 0);
                s[n] = __builtin_amdgcn_mfma_f32_16x16x32_bf16(qa1, kb1, s[n], 0, 0, 0);
            }
            __builtin_amdgcn_s_setprio(0);

            // P = exp2(S), causal zeroing on diag tile only
#pragma unroll
            for (int n = 0; n < 4; n++) {
#pragma unroll
                for (int r = 0; r < 4; r++) {
                    float pv = fexp2(s[n][r]);
                    if (diag) {
                        const int key = k0 + n * 16 + li;
                        if (key > myrow0 + r) pv = 0.0f;
                    }
                    Pl[wid * 16 + lg * 4 + r][((2 * n + (li >> 3) + 2 * lg) & 7) * 8 + (li & 7)] = f2bf(pv);
                }
            }

            if (pre) {  // V regs have arrived; fill Vt[next]
#pragma unroll
                for (int j = 0; j < 8; j++)
                    Vt[cur ^ 1][vx * 8 + j][((wid ^ j ^ vx) & 7) * 8 + srow] = vr0[j];
#pragma unroll
                for (int j = 0; j < 8; j++)
                    Vt[cur ^ 1][vx * 8 + j][(((wid + 4) ^ j ^ vx) & 7) * 8 + srow] = vr1[j];
            }

            // O += P V ; row-sums via ones-MFMA
            __builtin_amdgcn_s_setprio(1);
#pragma unroll
            for (int ks = 0; ks < 2; ks++) {
                const bf16x8 pa = *reinterpret_cast<const bf16x8*>(
                    &Pl[wid * 16 + li][((ks * 4 + lg + 2 * (li >> 2)) & 7) * 8]);
#pragma unroll
                for (int n = 0; n < 4; n++) {
                    const int row = n * 16 + li;
                    const bf16x8 vb = *reinterpret_cast<const bf16x8*>(
                        &Vt[cur][row][(((ks * 4 + lg) ^ (row & 7) ^ (row >> 3)) & 7) * 8]);
                    acc[n] = __builtin_amdgcn_mfma_f32_16x16x32_bf16(pa, vb, acc[n], 0, 0, 0);
                }
                accl = __builtin_amdgcn_mfma_f32_16x16x32_bf16(pa, ones, accl, 0, 0, 0);
            }
            __builtin_amdgcn_s_setprio(0);

            __syncthreads();
            cur ^= 1;
        };

        for (int t = 0; t < qt; t++) tile_body(t, false, true);
        tile_body(qt, true, false);

#pragma unroll
        for (int r = 0; r < 4; r++) {
            const float inv = 1.0f / accl[r];
            const int row = myrow0 + r;
#pragma unroll
            for (int n = 0; n < 4; n++)
                O[baseO + (size_t)row * HD + n * 16 + li] = f2bf(acc[n][r] * inv);
        }
    }
}

// ---------------- launch ----------------
extern "C" void kernel_launch(void* const* d_in, const int* in_sizes, int n_in,
                              void* d_out, int out_size, void* d_ws, size_t ws_size,
                              hipStream_t stream) {
    constexpr int B = 4, C = 2048, E = 1024, H = 16, FF = 4096;
    constexpr int M = B * C;  // 8192

    const float* x     = (const float*)d_in[0];
    const float* ln1_g = (const float*)d_in[1];
    const float* ln1_b = (const float*)d_in[2];
    const float* Wq    = (const float*)d_in[3];
    const float* Wk    = (const float*)d_in[4];
    const float* Wv    = (const float*)d_in[5];
    const float* Wo    = (const float*)d_in[6];
    const float* ln2_g = (const float*)d_in[7];
    const float* ln2_b = (const float*)d_in[8];
    const float* W1    = (const float*)d_in[9];
    const float* b1    = (const float*)d_in[10];
    const float* W2    = (const float*)d_in[11];
    const float* b2    = (const float*)d_in[12];

    char* p = (char*)d_ws;
    auto alloc = [&](size_t bytes) { void* r = (void*)p; p += (bytes + 255) & ~(size_t)255; return r; };
    unsigned short* WqT  = (unsigned short*)alloc((size_t)E * E * 2);   // Wq/Wk/Wv/Wo contiguous
    unsigned short* WkT  = (unsigned short*)alloc((size_t)E * E * 2);
    unsigned short* WvT  = (unsigned short*)alloc((size_t)E * E * 2);
    unsigned short* WoT  = (unsigned short*)alloc((size_t)E * E * 2);
    unsigned short* W1T  = (unsigned short*)alloc((size_t)E * FF * 2);
    unsigned short* W2T  = (unsigned short*)alloc((size_t)FF * E * 2);
    unsigned short* hb   = (unsigned short*)alloc((size_t)M * E * 2);
    unsigned short* QKVb = (unsigned short*)alloc((size_t)M * 3 * E * 2);
    unsigned short* attn = (unsigned short*)alloc((size_t)M * E * 2);
    float*          x1   = (float*)alloc((size_t)M * E * 4);
    unsigned short* h2   = (unsigned short*)alloc((size_t)M * E * 2);
    unsigned short* ff   = (unsigned short*)alloc((size_t)M * FF * 2);
    (void)WkT; (void)WvT;

    // weight conversion / transpose (4 square ones fused)
    convT4_kernel<<<dim3(E / 32, E / 32, 4), 256, 0, stream>>>(Wq, Wk, Wv, Wo, WqT);
    convT_kernel<<<dim3(FF / 32, E / 32), 256, 0, stream>>>(W1, W1T, E, FF);
    convT_kernel<<<dim3(E / 32, FF / 32), 256, 0, stream>>>(W2, W2T, FF, E);

    // LN1
    ln_kernel<<<M, 256, 0, stream>>>(x, ln1_g, ln1_b, hb);

    // fused QKV projection (N=3072), Q columns pre-scaled
    gemm_kernel<5><<<dim3((3 * E / 256) * (M / 256)), 512, 0, stream>>>(
        hb, WqT, nullptr, nullptr, QKVb, M, 3 * E, E);

    // attention
    flash_kernel<<<dim3(1024), 256, 0, stream>>>(QKVb, attn);

    // output projection + residual
    gemm_kernel<1><<<dim3((E / 256) * (M / 256)), 512, 0, stream>>>(
        attn, WoT, nullptr, x, x1, M, E, E);

    // LN2
    ln_kernel<<<M, 256, 0, stream>>>(x1, ln2_g, ln2_b, h2);

    // FFN
    gemm_kernel<2><<<dim3((FF / 256) * (M / 256)), 512, 0, stream>>>(
        h2, W1T, b1, nullptr, ff, M, FF, E);
    gemm_kernel<3><<<dim3((E / 256) * (M / 256)), 512, 0, stream>>>(
        ff, W2T, b2, x1, d_out, M, E, FF);
}

// Round 9
// 374.520 us; speedup vs baseline: 1.1108x; 1.0955x over previous
//
#include <hip/hip_runtime.h>

typedef __bf16 bf16x8 __attribute__((ext_vector_type(8)));
typedef float f32x4 __attribute__((ext_vector_type(4)));
typedef unsigned short u16x8 __attribute__((ext_vector_type(8)));
typedef unsigned short u16x4 __attribute__((ext_vector_type(4)));

__device__ __forceinline__ unsigned short f2bf(float f) {
    return __builtin_bit_cast(unsigned short, (__bf16)f);  // v_cvt RNE
}

__device__ __forceinline__ float fexp2(float x) {
#if __has_builtin(__builtin_amdgcn_exp2f)
    return __builtin_amdgcn_exp2f(x);
#else
    float r; asm("v_exp_f32 %0, %1\n\ts_nop 1" : "=v"(r) : "v"(x)); return r;
#endif
}

__device__ __forceinline__ void gload_lds16(const unsigned short* g, unsigned short* l) {
    __builtin_amdgcn_global_load_lds(
        (const __attribute__((address_space(1))) unsigned int*)g,
        (__attribute__((address_space(3))) unsigned int*)l, 16, 0, 0);
}

#define VMW(n) asm volatile("s_waitcnt vmcnt(" #n ")" ::: "memory")
#define SBAR() __builtin_amdgcn_s_barrier()
#define SCHED0() __builtin_amdgcn_sched_barrier(0)

// Q pre-scale: 1/sqrt(64) * log2(e), folded into the QKV GEMM epilogue (Q cols only)
#define QSCALE 0.18033688011112042f

// ---------------- LayerNorm: fp32 in -> bf16 out (E=1024, one row per block) ----------------
__global__ __launch_bounds__(256) void ln_kernel(
    const float* __restrict__ x, const float* __restrict__ g,
    const float* __restrict__ b, unsigned short* __restrict__ out)
{
    const int row = blockIdx.x;
    const int tid = threadIdx.x;
    const float4 v = reinterpret_cast<const float4*>(x + (size_t)row * 1024)[tid];
    float s = v.x + v.y + v.z + v.w;
    float q = v.x * v.x + v.y * v.y + v.z * v.z + v.w * v.w;
#pragma unroll
    for (int off = 32; off >= 1; off >>= 1) {
        s += __shfl_xor(s, off);
        q += __shfl_xor(q, off);
    }
    __shared__ float ss[4], sq[4];
    const int wid = tid >> 6, lane = tid & 63;
    if (lane == 0) { ss[wid] = s; sq[wid] = q; }
    __syncthreads();
    s = ss[0] + ss[1] + ss[2] + ss[3];
    q = sq[0] + sq[1] + sq[2] + sq[3];
    const float mu = s * (1.0f / 1024.0f);
    const float var = q * (1.0f / 1024.0f) - mu * mu;
    const float rs = rsqrtf(var + 1e-5f);
    const float4 gv = reinterpret_cast<const float4*>(g)[tid];
    const float4 bv = reinterpret_cast<const float4*>(b)[tid];
    u16x4 o;
    o[0] = f2bf((v.x - mu) * rs * gv.x + bv.x);
    o[1] = f2bf((v.y - mu) * rs * gv.y + bv.y);
    o[2] = f2bf((v.z - mu) * rs * gv.z + bv.z);
    o[3] = f2bf((v.w - mu) * rs * gv.w + bv.w);
    reinterpret_cast<u16x4*>(out + (size_t)row * 1024)[tid] = o;
}

// ---------------- Weight convert + transpose: W[K][N] fp32 -> Wt[N][K] bf16 ----------------
__global__ __launch_bounds__(256) void convT_kernel(
    const float* __restrict__ W, unsigned short* __restrict__ Wt, int K, int N)
{
    __shared__ float t[32][33];
    const int n0 = blockIdx.x * 32, k0 = blockIdx.y * 32;
    const int tx = threadIdx.x & 31;
    const int ty = threadIdx.x >> 5;
#pragma unroll
    for (int i = 0; i < 4; i++)
        t[ty + 8 * i][tx] = W[(size_t)(k0 + ty + 8 * i) * N + (n0 + tx)];
    __syncthreads();
#pragma unroll
    for (int i = 0; i < 4; i++)
        Wt[(size_t)(n0 + ty + 8 * i) * K + (k0 + tx)] = f2bf(t[tx][ty + 8 * i]);
}

// 4 square E x E transposes in one dispatch (z picks the matrix; dsts contiguous)
__global__ __launch_bounds__(256) void convT4_kernel(
    const float* __restrict__ A0, const float* __restrict__ A1,
    const float* __restrict__ A2, const float* __restrict__ A3,
    unsigned short* __restrict__ Wt)
{
    constexpr int E = 1024;
    const int z = blockIdx.z;
    const float* W = (z == 0) ? A0 : (z == 1) ? A1 : (z == 2) ? A2 : A3;
    unsigned short* dst = Wt + (size_t)z * E * E;
    __shared__ float t[32][33];
    const int n0 = blockIdx.x * 32, k0 = blockIdx.y * 32;
    const int tx = threadIdx.x & 31;
    const int ty = threadIdx.x >> 5;
#pragma unroll
    for (int i = 0; i < 4; i++)
        t[ty + 8 * i][tx] = W[(size_t)(k0 + ty + 8 * i) * E + (n0 + tx)];
    __syncthreads();
#pragma unroll
    for (int i = 0; i < 4; i++)
        dst[(size_t)(n0 + ty + 8 * i) * E + (k0 + tx)] = f2bf(t[tx][ty + 8 * i]);
}

// ---------------- 128x128 m97-structure GEMM (proven r5): out fp32 = acc + resid ------------
__global__ __launch_bounds__(256) void gemm128_kernel(
    const unsigned short* __restrict__ A, const unsigned short* __restrict__ Bt,
    const float* __restrict__ resid, float* __restrict__ out, int M, int N, int K)
{
    __shared__ unsigned short Al[128][64];
    __shared__ unsigned short Bl[128][64];
    const int tid = threadIdx.x;
    const int lane = tid & 63, wid = tid >> 6;
    const int wr = wid >> 1, wc = wid & 1;
    const int li = lane & 15, lg = lane >> 4;
    const int m0 = blockIdx.y * 128, n0 = blockIdx.x * 128;
    const int srow = lane >> 3;
    const int schunk = ((lane & 7) ^ srow) * 8;
    const unsigned short* Asrc = A + (size_t)(m0 + wid * 32 + srow) * K + schunk;
    const unsigned short* Bsrc = Bt + (size_t)(n0 + wid * 32 + srow) * K + schunk;
    f32x4 acc[4][4] = {};

    for (int k0 = 0; k0 < K; k0 += 64) {
        __syncthreads();
#pragma unroll
        for (int i = 0; i < 4; i++) {
            gload_lds16(Asrc + k0 + (size_t)i * 8 * K, &Al[wid * 32 + i * 8][0]);
            gload_lds16(Bsrc + k0 + (size_t)i * 8 * K, &Bl[wid * 32 + i * 8][0]);
        }
        __syncthreads();
#pragma unroll
        for (int ks = 0; ks < 2; ks++) {
            bf16x8 af[4], bfr[4];
#pragma unroll
            for (int m = 0; m < 4; m++)
                af[m] = *reinterpret_cast<const bf16x8*>(
                    &Al[wr * 64 + m * 16 + li][((ks * 4 + lg) ^ (li & 7)) * 8]);
#pragma unroll
            for (int n = 0; n < 4; n++)
                bfr[n] = *reinterpret_cast<const bf16x8*>(
                    &Bl[wc * 64 + n * 16 + li][((ks * 4 + lg) ^ (li & 7)) * 8]);
#pragma unroll
            for (int m = 0; m < 4; m++)
#pragma unroll
                for (int n = 0; n < 4; n++)
                    acc[m][n] = __builtin_amdgcn_mfma_f32_16x16x32_bf16(af[m], bfr[n], acc[m][n], 0, 0, 0);
        }
    }

#pragma unroll
    for (int m = 0; m < 4; m++)
#pragma unroll
        for (int r = 0; r < 4; r++) {
            const int row = m0 + wr * 64 + m * 16 + lg * 4 + r;
#pragma unroll
            for (int n = 0; n < 4; n++) {
                const int col = n0 + wc * 64 + n * 16 + li;
                out[(size_t)row * N + col] = acc[m][n][r] + resid[(size_t)row * N + col];
            }
        }
}

// ---------------- 256x256 8-phase GEMM (T2+T3+T4+T5+T1): C = A[M][K] * Bt[N][K]^T -----------
// 512 thr = 8 waves (2M x 4N), per-wave 128x64 (acc[8][4]). BK=64, 2 K-tiles/iter, 8 phases.
// Stage map (iter I, u0=2I): ph1/2: A(u0+1) h0/h1; ph3/4: B(u0+2) h0/h1; ph5/6: A(u0+2);
// ph7/8: B(u0+3) [staged whenever hn — B(2NI-1) comes from iter NI-2!]. vmcnt(4) ONLY at
// ph4/ph8 (tail: vmcnt(0)). Ledger: 12 outstanding at each counted wait -> 8 oldest (the
// tile needed next phase) complete, 4 newest (just-issued B) stay in flight.
// EPI 2: bf16 gelu(acc+bias); EPI 4: fp32 raw partial (split-K); EPI 5: bf16 QKV.
template <int EPI, int SPLITK>
__global__ __launch_bounds__(512, 2) void gemm256_kernel(
    const unsigned short* __restrict__ A, const unsigned short* __restrict__ Bt,
    const float* __restrict__ bias, void* __restrict__ out, int M, int N, int K)
{
    __shared__ __align__(16) unsigned short Al[2][256][64];   // 64 KB
    __shared__ __align__(16) unsigned short Bl[2][256][64];   // 64 KB
    const int tid = threadIdx.x;
    const int lane = tid & 63, wid = tid >> 6;   // 8 waves
    const int wr = wid >> 2, wc = wid & 3;       // 2M x 4N wave grid
    const int li = lane & 15, lg = lane >> 4;

    // bijective XCD-chunked swizzle (all grids are multiples of 8)
    const int nblk = (M >> 8) * (N >> 8);        // tiles per K-split
    const int cpx = gridDim.x >> 3;
    const int swz = ((int)blockIdx.x & 7) * cpx + ((int)blockIdx.x >> 3);
    int tsw = swz, sid = 0;
    if (SPLITK == 2) { sid = (swz >= nblk) ? 1 : 0; tsw = swz - sid * nblk; }
    const int nx = N >> 8;
    const int bx = tsw % nx, by = tsw / nx;
    const int m0 = by * 256, n0 = bx * 256;
    const int kOff = (SPLITK == 2) ? sid * (K >> 1) : 0;
    const int kLen = (SPLITK == 2) ? (K >> 1) : K;

    // staging: wave w covers rows [w*16, w*16+16) of each 128-row half (2 gload_lds).
    // LDS chunk (row, c) holds global chunk c ^ (row&7) -> pre-swizzled source (T21).
    const int srow = lane >> 3;
    const int sgc = ((lane & 7) ^ srow) * 8;
    const unsigned short* aSrc = A + (size_t)(m0 + wid * 16 + srow) * K + kOff + sgc;
    const unsigned short* bSrc = Bt + (size_t)(n0 + wid * 16 + srow) * K + kOff + sgc;
    unsigned short* aDst = &Al[0][wid * 16][0];
    unsigned short* bDst = &Bl[0][wid * 16][0];

    auto stA = [&](int u, int h) {               // A half h of K-tile u -> buf u&1
        const unsigned short* s = aSrc + (size_t)(h * 128) * K + u * 64;
        unsigned short* d = aDst + (u & 1) * (256 * 64) + h * 128 * 64;
        gload_lds16(s, d);
        gload_lds16(s + (size_t)8 * K, d + 8 * 64);
    };
    auto stB = [&](int u, int h) {
        const unsigned short* s = bSrc + (size_t)(h * 128) * K + u * 64;
        unsigned short* d = bDst + (u & 1) * (256 * 64) + h * 128 * 64;
        gload_lds16(s, d);
        gload_lds16(s + (size_t)8 * K, d + 8 * 64);
    };

    f32x4 acc[8][4] = {};
    bf16x8 af[8], bn0[4], bn1[4];

    auto ldA = [&](int buf, int mh) {            // 8 x ds_read_b128
#pragma unroll
        for (int m = 0; m < 4; m++)
#pragma unroll
            for (int ks = 0; ks < 2; ks++)
                af[m * 2 + ks] = *reinterpret_cast<const bf16x8*>(
                    &Al[buf][wr * 128 + mh * 64 + m * 16 + li][((ks * 4 + lg) ^ (li & 7)) * 8]);
    };
    auto ldB = [&](bf16x8* dst, int buf, int nh) {  // 4 x ds_read_b128
#pragma unroll
        for (int n = 0; n < 2; n++)
#pragma unroll
            for (int ks = 0; ks < 2; ks++)
                dst[n * 2 + ks] = *reinterpret_cast<const bf16x8*>(
                    &Bl[buf][wc * 64 + nh * 32 + n * 16 + li][((ks * 4 + lg) ^ (li & 7)) * 8]);
    };
    auto quad = [&](const bf16x8* bfr, int mh, int nh) {   // 16 MFMA: one C-quadrant x K=64
        __builtin_amdgcn_s_setprio(1);
#pragma unroll
        for (int ks = 0; ks < 2; ks++)
#pragma unroll
            for (int m = 0; m < 4; m++)
#pragma unroll
                for (int n = 0; n < 2; n++)
                    acc[mh * 4 + m][nh * 2 + n] = __builtin_amdgcn_mfma_f32_16x16x32_bf16(
                        af[m * 2 + ks], bfr[n * 2 + ks], acc[mh * 4 + m][nh * 2 + n], 0, 0, 0);
        __builtin_amdgcn_s_setprio(0);
    };

    const int NI = kLen >> 7;                    // iterations of 2 K-tiles (>= 4 here)

    // prologue: A(0), B(0) then B(1); vmcnt(4) -> tile0 landed, tile1-B in flight
    stA(0, 0); stA(0, 1); stB(0, 0); stB(0, 1);
    stB(1, 0); stB(1, 1);
    VMW(4);
    SBAR(); SCHED0();

    for (int I = 0; I < NI; ++I) {
        const int u0 = 2 * I;
        const bool hn = (I + 1 < NI);
        // ---- K-tile u0 (buf 0) ----
        // ph1
        ldA(0, 0); ldB(bn0, 0, 0);
        stA(u0 + 1, 0);
        SBAR(); SCHED0();
        quad(bn0, 0, 0);
        SBAR(); SCHED0();
        // ph2
        ldB(bn1, 0, 1);
        stA(u0 + 1, 1);
        SBAR(); SCHED0();
        quad(bn1, 0, 1);
        SBAR(); SCHED0();
        // ph3
        ldA(0, 1);
        if (hn) stB(u0 + 2, 0);
        SBAR(); SCHED0();
        quad(bn1, 1, 1);
        SBAR(); SCHED0();
        // ph4 (bn0 held since ph1)
        if (hn) stB(u0 + 2, 1);
        SBAR(); SCHED0();
        quad(bn0, 1, 0);
        if (hn) { VMW(4); } else { VMW(0); }
        SBAR(); SCHED0();
        // ---- K-tile u0+1 (buf 1) ----
        // ph5
        ldA(1, 0); ldB(bn0, 1, 0);
        if (hn) stA(u0 + 2, 0);
        SBAR(); SCHED0();
        quad(bn0, 0, 0);
        SBAR(); SCHED0();
        // ph6
        ldB(bn1, 1, 1);
        if (hn) stA(u0 + 2, 1);
        SBAR(); SCHED0();
        quad(bn1, 0, 1);
        SBAR(); SCHED0();
        // ph7  [FIX r8: guard is hn, NOT hn && I+2<NI — B(2NI-1) is staged at iter NI-2]
        ldA(1, 1);
        if (hn) stB(u0 + 3, 0);
        SBAR(); SCHED0();
        quad(bn1, 1, 1);
        SBAR(); SCHED0();
        // ph8
        if (hn) stB(u0 + 3, 1);
        SBAR(); SCHED0();
        quad(bn0, 1, 0);
        if (hn) { VMW(4); } else { VMW(0); }
        SBAR(); SCHED0();
    }

    // epilogue
#pragma unroll
    for (int ma = 0; ma < 8; ma++) {
#pragma unroll
        for (int r = 0; r < 4; r++) {
            const int row = m0 + wr * 128 + ma * 16 + lg * 4 + r;
#pragma unroll
            for (int n = 0; n < 4; n++) {
                const int col = n0 + wc * 64 + n * 16 + li;
                float v = acc[ma][n][r];
                if constexpr (EPI == 2) {
                    v += bias[col];
                    float a2 = 1.5957691216f * (v + 0.044715f * v * v * v);
                    a2 = fminf(a2, 80.0f);
                    const float t = __expf(a2);
                    v = v * t * __builtin_amdgcn_rcpf(t + 1.0f);
                    reinterpret_cast<unsigned short*>(out)[(size_t)row * N + col] = f2bf(v);
                } else if constexpr (EPI == 4) {  // raw fp32 partial (split-K)
                    float* op = reinterpret_cast<float*>(out) + (size_t)sid * M * N;
                    op[(size_t)row * N + col] = v;
                } else {  // EPI 5: fused QKV, Q columns pre-scaled for exp2 softmax
                    const float sc = (col < 1024) ? QSCALE : 1.0f;
                    reinterpret_cast<unsigned short*>(out)[(size_t)row * N + col] = f2bf(v * sc);
                }
            }
        }
    }
}

// ---------------- W2 split-K reduce: d_out = p0 + p1 + b2 + x1 ----------------
__global__ __launch_bounds__(256) void w2red_kernel(
    const float* __restrict__ p0, const float* __restrict__ p1,
    const float* __restrict__ x1, const float* __restrict__ b2,
    float* __restrict__ out)
{
    const int i = blockIdx.x * 256 + threadIdx.x;     // float4 index
    const float4 a = reinterpret_cast<const float4*>(p0)[i];
    const float4 b = reinterpret_cast<const float4*>(p1)[i];
    const float4 r = reinterpret_cast<const float4*>(x1)[i];
    const float4 bb = reinterpret_cast<const float4*>(b2)[i & 255];
    float4 o;
    o.x = a.x + b.x + r.x + bb.x;
    o.y = a.y + b.y + r.y + bb.y;
    o.z = a.z + b.z + r.z + bb.z;
    o.w = a.w + b.w + r.w + bb.w;
    reinterpret_cast<float4*>(out)[i] = o;
}

// ---------------- Flash attention (causal), no-max exp2 softmax, 1 barrier/tile ----------------
// QKV [8192][3072] (Q pre-scaled by QSCALE). grid 1024 = 4 blocks/CU exactly resident.
__global__ __launch_bounds__(256, 4) void flash_kernel(
    const unsigned short* __restrict__ QKV, unsigned short* __restrict__ O)
{
    constexpr int C = 2048, HD3 = 3072, HD = 1024, NT = 32;
    __shared__ unsigned short Kl[2][64][64];  // [key][d], chunk XOR (row&7)
    __shared__ unsigned short Vt[2][64][64];  // [d][key], chunk XOR
    __shared__ unsigned short Pl[64][64];     // [q][key], chunk rotation
    const int tid = threadIdx.x;
    const int lane = tid & 63, wid = tid >> 6;
    const int li = lane & 15, lg = lane >> 4;
    const int flat = blockIdx.x;
    const int bh = flat & 63;
    const int pair = flat >> 6;
    const int b = bh >> 4, h = bh & 15;
    const size_t baseQ = ((size_t)b * C) * HD3 + (size_t)h * 64;
    const size_t baseK = baseQ + 1024;
    const size_t baseV = baseQ + 2048;
    const size_t baseO = ((size_t)b * C) * HD + (size_t)h * 64;

    const int srow = lane >> 3;
    const int sgc = ((lane & 7) ^ srow) * 8;
    const int vx = lane & 7;

    const u16x8 onesu = {0x3F80, 0x3F80, 0x3F80, 0x3F80, 0x3F80, 0x3F80, 0x3F80, 0x3F80};
    const bf16x8 ones = __builtin_bit_cast(bf16x8, onesu);

    for (int half = 0; half < 2; half++) {
        const int qt = (half == 0) ? pair : (NT - 1 - pair);
        const int q0 = qt * 64;
        const int qrow = q0 + wid * 16 + li;
        const bf16x8 qa0 = *reinterpret_cast<const bf16x8*>(&QKV[baseQ + (size_t)qrow * HD3 + lg * 8]);
        const bf16x8 qa1 = *reinterpret_cast<const bf16x8*>(&QKV[baseQ + (size_t)qrow * HD3 + 32 + lg * 8]);
        const int myrow0 = q0 + wid * 16 + lg * 4;

        f32x4 acc[4] = {};
        f32x4 accl = {};
        int cur = 0;

        auto stage = [&](int k0s, int buf) {
#pragma unroll
            for (int i = 0; i < 2; i++)
                gload_lds16(&QKV[baseK + (size_t)(k0s + wid * 16 + i * 8 + srow) * HD3 + sgc],
                            &Kl[buf][wid * 16 + i * 8][0]);
#pragma unroll
            for (int i = 0; i < 2; i++) {
                const int lkey = 8 * wid + srow + 32 * i;
                const u16x8 vv = *reinterpret_cast<const u16x8*>(
                    &QKV[baseV + (size_t)(k0s + lkey) * HD3 + vx * 8]);
                const int vc = wid + 4 * i;
#pragma unroll
                for (int j = 0; j < 8; j++)
                    Vt[buf][vx * 8 + j][((vc ^ j ^ vx) & 7) * 8 + srow] = vv[j];
            }
        };

        __syncthreads();
        stage(0, 0);
        __syncthreads();

        auto tile_body = [&](int t, bool diag, bool pre) {
            const int k0 = t * 64;
            u16x8 vr0, vr1;
            if (pre) {
                const int kn = k0 + 64;
#pragma unroll
                for (int i = 0; i < 2; i++)
                    gload_lds16(&QKV[baseK + (size_t)(kn + wid * 16 + i * 8 + srow) * HD3 + sgc],
                                &Kl[cur ^ 1][wid * 16 + i * 8][0]);
                vr0 = *reinterpret_cast<const u16x8*>(
                    &QKV[baseV + (size_t)(kn + 8 * wid + srow) * HD3 + vx * 8]);
                vr1 = *reinterpret_cast<const u16x8*>(
                    &QKV[baseV + (size_t)(kn + 8 * wid + srow + 32) * HD3 + vx * 8]);
            }

            f32x4 s[4] = {};
            __builtin_amdgcn_s_setprio(1);
#pragma unroll
            for (int n = 0; n < 4; n++) {
                const int row = n * 16 + li;
                const bf16x8 kb0 = *reinterpret_cast<const bf16x8*>(
                    &Kl[cur][row][(lg ^ (li & 7)) * 8]);
                const bf16x8 kb1 = *reinterpret_cast<const bf16x8*>(
                    &Kl[cur][row][((4 + lg) ^ (li & 7)) * 8]);
                s[n] = __builtin_amdgcn_mfma_f32_16x16x32_bf16(qa0, kb0, s[n], 0, 0, 0);
                s[n] = __builtin_amdgcn_mfma_f32_16x16x32_bf16(qa1, kb1, s[n], 0, 0, 0);
            }
            __builtin_amdgcn_s_setprio(0);

#pragma unroll
            for (int n = 0; n < 4; n++) {
#pragma unroll
                for (int r = 0; r < 4; r++) {
                    float pv = fexp2(s[n][r]);
                    if (diag) {
                        const int key = k0 + n * 16 + li;
                        if (key > myrow0 + r) pv = 0.0f;
                    }
                    Pl[wid * 16 + lg * 4 + r][((2 * n + (li >> 3) + 2 * lg) & 7) * 8 + (li & 7)] = f2bf(pv);
                }
            }

            if (pre) {
#pragma unroll
                for (int j = 0; j < 8; j++)
                    Vt[cur ^ 1][vx * 8 + j][((wid ^ j ^ vx) & 7) * 8 + srow] = vr0[j];
#pragma unroll
                for (int j = 0; j < 8; j++)
                    Vt[cur ^ 1][vx * 8 + j][(((wid + 4) ^ j ^ vx) & 7) * 8 + srow] = vr1[j];
            }

            __builtin_amdgcn_s_setprio(1);
#pragma unroll
            for (int ks = 0; ks < 2; ks++) {
                const bf16x8 pa = *reinterpret_cast<const bf16x8*>(
                    &Pl[wid * 16 + li][((ks * 4 + lg + 2 * (li >> 2)) & 7) * 8]);
#pragma unroll
                for (int n = 0; n < 4; n++) {
                    const int row = n * 16 + li;
                    const bf16x8 vb = *reinterpret_cast<const bf16x8*>(
                        &Vt[cur][row][(((ks * 4 + lg) ^ (row & 7) ^ (row >> 3)) & 7) * 8]);
                    acc[n] = __builtin_amdgcn_mfma_f32_16x16x32_bf16(pa, vb, acc[n], 0, 0, 0);
                }
                accl = __builtin_amdgcn_mfma_f32_16x16x32_bf16(pa, ones, accl, 0, 0, 0);
            }
            __builtin_amdgcn_s_setprio(0);

            __syncthreads();
            cur ^= 1;
        };

        for (int t = 0; t < qt; t++) tile_body(t, false, true);
        tile_body(qt, true, false);

#pragma unroll
        for (int r = 0; r < 4; r++) {
            const float inv = 1.0f / accl[r];
            const int row = myrow0 + r;
#pragma unroll
            for (int n = 0; n < 4; n++)
                O[baseO + (size_t)row * HD + n * 16 + li] = f2bf(acc[n][r] * inv);
        }
    }
}

// ---------------- launch ----------------
extern "C" void kernel_launch(void* const* d_in, const int* in_sizes, int n_in,
                              void* d_out, int out_size, void* d_ws, size_t ws_size,
                              hipStream_t stream) {
    constexpr int B = 4, C = 2048, E = 1024, H = 16, FF = 4096;
    constexpr int M = B * C;  // 8192

    const float* x     = (const float*)d_in[0];
    const float* ln1_g = (const float*)d_in[1];
    const float* ln1_b = (const float*)d_in[2];
    const float* Wq    = (const float*)d_in[3];
    const float* Wk    = (const float*)d_in[4];
    const float* Wv    = (const float*)d_in[5];
    const float* Wo    = (const float*)d_in[6];
    const float* ln2_g = (const float*)d_in[7];
    const float* ln2_b = (const float*)d_in[8];
    const float* W1    = (const float*)d_in[9];
    const float* b1    = (const float*)d_in[10];
    const float* W2    = (const float*)d_in[11];
    const float* b2    = (const float*)d_in[12];

    char* p = (char*)d_ws;
    auto alloc = [&](size_t bytes) { void* r = (void*)p; p += (bytes + 255) & ~(size_t)255; return r; };
    unsigned short* WqT  = (unsigned short*)alloc((size_t)E * E * 2);   // Wq/Wk/Wv/Wo contiguous
    unsigned short* WkT  = (unsigned short*)alloc((size_t)E * E * 2);
    unsigned short* WvT  = (unsigned short*)alloc((size_t)E * E * 2);
    unsigned short* WoT  = (unsigned short*)alloc((size_t)E * E * 2);
    unsigned short* W1T  = (unsigned short*)alloc((size_t)E * FF * 2);
    unsigned short* W2T  = (unsigned short*)alloc((size_t)FF * E * 2);
    unsigned short* hb   = (unsigned short*)alloc((size_t)M * E * 2);   // reused as W2 partials
    unsigned short* QKVb = (unsigned short*)alloc((size_t)M * 3 * E * 2);
    unsigned short* attn = (unsigned short*)alloc((size_t)M * E * 2);
    float*          x1   = (float*)alloc((size_t)M * E * 4);
    unsigned short* h2   = (unsigned short*)alloc((size_t)M * E * 2);
    unsigned short* ff   = (unsigned short*)alloc((size_t)M * FF * 2);
    (void)WkT; (void)WvT;
    float* parts = (float*)hb;  // 64 MB: spans hb+QKVb (both dead after flash/Wo)

    // weight conversion / transpose
    convT4_kernel<<<dim3(E / 32, E / 32, 4), 256, 0, stream>>>(Wq, Wk, Wv, Wo, WqT);
    convT_kernel<<<dim3(FF / 32, E / 32), 256, 0, stream>>>(W1, W1T, E, FF);
    convT_kernel<<<dim3(E / 32, FF / 32), 256, 0, stream>>>(W2, W2T, FF, E);

    // LN1
    ln_kernel<<<M, 256, 0, stream>>>(x, ln1_g, ln1_b, hb);

    // fused QKV projection (N=3072), Q columns pre-scaled; 8-phase 256^2, grid 384
    gemm256_kernel<5, 1><<<dim3((3 * E / 256) * (M / 256)), 512, 0, stream>>>(
        hb, WqT, nullptr, QKVb, M, 3 * E, E);

    // attention
    flash_kernel<<<dim3(1024), 256, 0, stream>>>(QKVb, attn);

    // output projection + residual (m97 128^2, grid 512 = 2/CU)
    gemm128_kernel<<<dim3(E / 128, M / 128), 256, 0, stream>>>(
        attn, WoT, x, x1, M, E, E);

    // LN2
    ln_kernel<<<M, 256, 0, stream>>>(x1, ln2_g, ln2_b, h2);

    // FFN up + GELU (8-phase 256^2, grid 512)
    gemm256_kernel<2, 1><<<dim3((FF / 256) * (M / 256)), 512, 0, stream>>>(
        h2, W1T, b1, ff, M, FF, E);

    // FFN down: split-K=2 (grid 256 = full machine), then reduce + bias + residual
    gemm256_kernel<4, 2><<<dim3(2 * (E / 256) * (M / 256)), 512, 0, stream>>>(
        ff, W2T, nullptr, parts, M, E, FF);
    w2red_kernel<<<dim3(M * E / 4 / 256), 256, 0, stream>>>(
        parts, parts + (size_t)M * E, x1, b2, (float*)d_out);
}